// Round 9
// baseline (2000.280 us; speedup 1.0000x reference)
//
#include <hip/hip_runtime.h>
#include <stdint.h>

#define Bsz 256
#define Tt  128
#define INs 256
#define Hh  512

typedef __attribute__((ext_vector_type(8))) short short8;
typedef __attribute__((ext_vector_type(4))) float f32x4;

__device__ __forceinline__ unsigned short f2bf(float f) {
  union { float f; unsigned int u; } v; v.f = f;
  unsigned int u = v.u;
  u += 0x7FFFu + ((u >> 16) & 1u);   // round-to-nearest-even
  return (unsigned short)(u >> 16);
}
__device__ __forceinline__ float bf2f(unsigned short h) {
  union { unsigned int u; float f; } v; v.u = ((unsigned int)h) << 16;
  return v.f;
}
__device__ __forceinline__ float sigf(float x) { return 1.0f / (1.0f + expf(-x)); }

#define AL32(P)   __hip_atomic_load((P), __ATOMIC_RELAXED, __HIP_MEMORY_SCOPE_AGENT)
#define AL64(P)   __hip_atomic_load((P), __ATOMIC_RELAXED, __HIP_MEMORY_SCOPE_AGENT)
#define AS(P, V)  __hip_atomic_store((P), (V), __ATOMIC_RELAXED, __HIP_MEMORY_SCOPE_AGENT)

// ---- ws layout (bytes) ----
// h element format: u64 = (tag16 << 48) | (h_odd16 << 16) | h_even16  (2 cols)
// tag for h written at step t is t+1; zeroed memory == tag 0 == h[-1] == 0.
#define WS_F1 0                                    // 4 groups x 128 wave-flags x 64B
#define WS_H0 32768                                // 4 slots x 256 x 256 u64 = 2 MB
#define WS_H1 (WS_H0 + 4 * 256 * 256 * 8)          // 2 slots x 256 x 256 u64 = 1 MB
#define WS_ZERO_BYTES (WS_H1 + 2 * 256 * 256 * 8)  // 3178496

#define W_BYTES   131072
#define DYN_SHMEM (W_BYTES + 64 * 4 + 48 * 4)

// ---- tag-polled h GEMM half: 16 ksteps, 4-kstep batches, 1-batch lookahead ----
#define LOADB(L, HB, KS0)                                                      \
  _Pragma("unroll")                                                            \
  for (int q = 0; q < 16; ++q)                                                 \
    L[q] = AL64((HB) + ((KS0) + (q >> 2)) * 16 + (q & 3));

#define SPINB(L, HB, KS0, TH)                                                  \
  for (;;) {                                                                   \
    unsigned int orv = 0;                                                      \
    _Pragma("unroll")                                                          \
    for (int q = 0; q < 16; ++q) orv |= ((unsigned int)(L[q] >> 32)) ^ (TH);   \
    if (__ballot(orv == 0) == ~0ull) break;                                    \
    __builtin_amdgcn_s_sleep(2);                                               \
    LOADB(L, HB, KS0)                                                          \
  }

#define MFMAB(L, KS0, KB)                                                      \
  _Pragma("unroll")                                                            \
  for (int k = 0; k < 4; ++k) {                                                \
    union { unsigned int w[4]; short8 s; } ua;                                 \
    ua.w[0] = (unsigned int)L[k * 4 + 0];                                      \
    ua.w[1] = (unsigned int)L[k * 4 + 1];                                      \
    ua.w[2] = (unsigned int)L[k * 4 + 2];                                      \
    ua.w[3] = (unsigned int)L[k * 4 + 3];                                      \
    _Pragma("unroll")                                                          \
    for (int c4 = 0; c4 < 4; ++c4) {                                           \
      short8 b = *(const short8*)(smem + ((((KS0) + k + (KB)) * 4 + c4) * 64 + lane) * 16); \
      acc[c4] = __builtin_amdgcn_mfma_f32_16x16x32_bf16(ua.s, b, acc[c4], 0, 0, 0);         \
    }                                                                          \
  }

#define H_HALF(HB, KB, TAG)                                                    \
  {                                                                            \
    const unsigned int TH = ((unsigned int)(TAG)) << 16;                       \
    unsigned long long LA[16], LB[16];                                         \
    LOADB(LA, HB, 0)                                                           \
    LOADB(LB, HB, 4)                                                           \
    SPINB(LA, HB, 0, TH)                                                       \
    MFMAB(LA, 0, KB)                                                           \
    LOADB(LA, HB, 8)                                                           \
    SPINB(LB, HB, 4, TH)                                                       \
    MFMAB(LB, 4, KB)                                                           \
    LOADB(LB, HB, 12)                                                          \
    SPINB(LA, HB, 8, TH)                                                       \
    MFMAB(LA, 8, KB)                                                           \
    SPINB(LB, HB, 12, TH)                                                      \
    MFMAB(LB, 12, KB)                                                          \
  }

// ---- in-register peephole elementwise; even lanes store tagged col-pairs ----
#define ELEMWISE_TAG(DSTU64, TAG)                                              \
  {                                                                            \
    const int jj = lane & 15;                                                  \
    const unsigned long long thi =                                             \
        ((unsigned long long)(((unsigned int)(TAG)) << 16)) << 32;             \
    _Pragma("unroll")                                                          \
    for (int v = 0; v < 4; ++v) {                                              \
      const int R = (wave << 4) + ((lane >> 4) << 2) + v;                      \
      float gi = acc[0][v] + bxl[jj];                                          \
      float gf = acc[1][v] + bxl[16 + jj];                                     \
      float gg = acc[2][v] + bxl[32 + jj];                                     \
      float go = acc[3][v] + bxl[48 + jj];                                     \
      float co = cr[v];                                                        \
      float iv = sigf(gi + co * wcl[jj]);                                      \
      float fv = sigf(gf + co * wcl[16 + jj]);                                 \
      float gv = tanhf(gg);                                                    \
      float cn = fv * co + iv * gv;                                            \
      float ov = sigf(go + cn * wcl[32 + jj]);                                 \
      cr[v] = cn;                                                              \
      unsigned int hv = (unsigned int)f2bf(ov * tanhf(cn));                    \
      unsigned int pv = (unsigned int)__builtin_amdgcn_ds_swizzle((int)hv, 0x041F); \
      if (!(lane & 1)) {                                                       \
        unsigned long long val = thi | (unsigned long long)((pv << 16) | hv);  \
        AS((DSTU64) + (size_t)((g << 6) + R) * 256 + (j0 >> 1) + (jj >> 1), val); \
      }                                                                        \
    }                                                                          \
  }

extern "C" __global__ void __launch_bounds__(256)
lstm_fused(const float* __restrict__ x,
           const float* __restrict__ Wx0, const float* __restrict__ bx0,
           const float* __restrict__ Wh0, const float* __restrict__ Wc0,
           const float* __restrict__ Wx1, const float* __restrict__ bx1,
           const float* __restrict__ Wh1, const float* __restrict__ Wc1,
           const float* __restrict__ Wfc, const float* __restrict__ bfc,
           float* __restrict__ out, unsigned char* __restrict__ ws)
{
  extern __shared__ char smem[];
  unsigned long long* h0u = (unsigned long long*)(ws + WS_H0);
  unsigned long long* h1u = (unsigned long long*)(ws + WS_H1);
  float* bxl = (float*)(smem + W_BYTES);
  float* wcl = bxl + 64;

  const int wg    = blockIdx.x;
  const int g     = wg >> 6;        // batch-row group (0..3), 64 rows each
  const int sub   = wg & 63;
  const int layer = sub >> 5;
  const int cb    = sub & 31;       // 16 hidden cols
  const int tid   = threadIdx.x;
  const int lane  = tid & 63;
  const int wave  = tid >> 6;
  const int j0    = cb << 4;

  int* f1base = (int*)(ws + WS_F1) + (g << 11);   // 128 wave-flags x 16-int stride

  // ---- preload this WG's weight slice into LDS, bf16, fragment order ----
  {
    const int K   = layer ? 1024 : 768;
    const int k8s = K >> 3;
    const int ng  = 64 * k8s;
    for (int idx = tid; idx < ng; idx += 256) {
      const int nl = idx / k8s;
      const int k8 = idx - nl * k8s;
      const int k  = k8 << 3;
      const int nrow = (nl >> 4) * Hh + j0 + (nl & 15);
      const float* src;
      if (!layer) src = (k < INs) ? (Wx0 + (size_t)nrow * INs + k)
                                  : (Wh0 + (size_t)nrow * Hh + (k - INs));
      else        src = (k < Hh)  ? (Wx1 + (size_t)nrow * Hh + k)
                                  : (Wh1 + (size_t)nrow * Hh + (k - Hh));
      short8 v;
      #pragma unroll
      for (int j = 0; j < 8; ++j) v[j] = (short)f2bf(src[j]);
      const int slot = ((k8 >> 2) * 4 + (nl >> 4)) * 64 + ((k8 & 3) * 16 + (nl & 15));
      *(short8*)(smem + slot * 16) = v;
    }
  }
  {
    const float* bx = layer ? bx1 : bx0;
    const float* Wc = layer ? Wc1 : Wc0;
    if (tid < 64) bxl[tid] = bx[(tid >> 4) * Hh + j0 + (tid & 15)];
    if (tid < 48) wcl[tid] = Wc[(tid >> 4) * Hh + j0 + (tid & 15)];
  }
  __syncthreads();

  // ---- wave tile: 16 rows x 64 gate-cols ----
  const int lr    = (wave << 4) + (lane & 15);  // local row 0..63
  const int bg    = (g << 6) + lr;              // global batch row
  const int koff  = (lane >> 4) << 3;           // shorts
  const size_t rbu = (size_t)bg * 256 + ((lane >> 4) << 2);  // u64 row base

  float cr[4] = {0.f, 0.f, 0.f, 0.f};
  const f32x4 zz = {0.f, 0.f, 0.f, 0.f};

  if (!layer) {
    // =============== LAYER 0 ===============
    for (int t = 0; t < Tt; ++t) {
      f32x4 acc[4] = {zz, zz, zz, zz};
      // x-part first (independent; overlaps peers' h0[t-1] stores landing)
      const float* xp = x + ((size_t)bg * Tt + t) * INs + koff;
      #pragma unroll 2
      for (int ks = 0; ks < 8; ++ks) {
        const float* s0 = xp + ks * 32;
        short8 a;
        #pragma unroll
        for (int j = 0; j < 8; ++j) a[j] = (short)f2bf(s0[j]);
        #pragma unroll
        for (int c4 = 0; c4 < 4; ++c4) {
          short8 b = *(const short8*)(smem + ((ks * 4 + c4) * 64 + lane) * 16);
          acc[c4] = __builtin_amdgcn_mfma_f32_16x16x32_bf16(a, b, acc[c4], 0, 0, 0);
        }
      }
      // h0[t-1] @ Wh0 (ksteps 8..23), slot (t-1)&3, tag t
      const unsigned long long* hb = h0u + (((size_t)((t + 3) & 3)) << 16) + rbu;
      H_HALF(hb, 8, t)
      // throttle: L1 wave-plane must have consumed h0[t-4] before slot reuse
      if (t >= 4) {
        const int tgt = t - 3;
        const int* fp_ = f1base + (((lane & 31) << 2) + wave) * 16;
        for (;;) {
          int v_ = AL32(fp_);
          if (__ballot(v_ >= tgt) == ~0ull) break;
          __builtin_amdgcn_s_sleep(2);
        }
      }
      ELEMWISE_TAG(h0u + (((size_t)(t & 3)) << 16), t + 1)
    }
  } else {
    // =============== LAYER 1 ===============
    for (int u = 0; u < Tt; ++u) {
      f32x4 acc[4] = {zz, zz, zz, zz};
      // h0[u] @ Wx1 (ksteps 0..15): L0 leads, data likely already landed
      const unsigned long long* ab = h0u + (((size_t)(u & 3)) << 16) + rbu;
      H_HALF(ab, 0, u + 1)
      // h1[u-1] @ Wh1 (ksteps 16..31), slot (u-1)&1, tag u
      const unsigned long long* bb2 = h1u + (((size_t)((u + 1) & 1)) << 16) + rbu;
      H_HALF(bb2, 16, u)
      // per-wave progress flag: certifies this wave's read of h0[u] is done
      if (lane == 0)
        AS(f1base + ((cb << 2) + wave) * 16, u + 1);
      ELEMWISE_TAG(h1u + (((size_t)(u & 1)) << 16), u + 1)
    }
  }

  // ---- final FC: poll h1[127] (slot 1, tag 128) directly on the data ----
  {
    const int cc = tid & 7, ksl = tid >> 3;
    const unsigned long long* hrow = h1u + ((size_t)1 << 16) + (size_t)wg * 256 + ksl * 8;
    const unsigned int THF = ((unsigned int)Tt) << 16;
    unsigned long long hv8[8];
    for (;;) {
      unsigned int orv = 0;
      #pragma unroll
      for (int q = 0; q < 8; ++q) hv8[q] = AL64(hrow + q);
      #pragma unroll
      for (int q = 0; q < 8; ++q) orv |= ((unsigned int)(hv8[q] >> 32)) ^ THF;
      if (orv == 0) break;
      __builtin_amdgcn_s_sleep(2);
    }
    const float* wr = Wfc + (size_t)cc * Hh + ksl * 16;
    float s = 0.f;
    #pragma unroll
    for (int q = 0; q < 8; ++q) {
      unsigned long long v = hv8[q];
      s += bf2f((unsigned short)v) * wr[2 * q]
         + bf2f((unsigned short)(v >> 16)) * wr[2 * q + 1];
    }
    float* red = (float*)smem;
    __syncthreads();           // weight-smem reads done before reuse
    red[tid] = s;
    __syncthreads();
    if (tid < 8) {
      float a = bfc[tid];
      #pragma unroll
      for (int i = 0; i < 32; ++i) a += red[i * 8 + tid];
      out[wg * 8 + tid] = a;
    }
  }
}

extern "C" void kernel_launch(void* const* d_in, const int* in_sizes, int n_in,
                              void* d_out, int out_size, void* d_ws, size_t ws_size,
                              hipStream_t stream) {
  if (ws_size < (size_t)WS_ZERO_BYTES) return;

  const float* x   = (const float*)d_in[0];
  const float* Wx0 = (const float*)d_in[1];
  const float* bx0 = (const float*)d_in[2];
  const float* Wh0 = (const float*)d_in[3];
  const float* Wc0 = (const float*)d_in[4];
  const float* Wx1 = (const float*)d_in[5];
  const float* bx1 = (const float*)d_in[6];
  const float* Wh1 = (const float*)d_in[7];
  const float* Wc1 = (const float*)d_in[8];
  const float* Wfc = (const float*)d_in[9];
  const float* bfc = (const float*)d_in[10];
  float* out = (float*)d_out;
  unsigned char* ws = (unsigned char*)d_ws;

  (void)hipMemsetAsync(d_ws, 0, WS_ZERO_BYTES, stream);
  (void)hipFuncSetAttribute(reinterpret_cast<const void*>(lstm_fused),
                            hipFuncAttributeMaxDynamicSharedMemorySize, DYN_SHMEM);
  void* args[] = {&x, &Wx0, &bx0, &Wh0, &Wc0, &Wx1, &bx1, &Wh1, &Wc1, &Wfc, &bfc, &out, &ws};
  (void)hipLaunchCooperativeKernel((void*)lstm_fused, dim3(256), dim3(256), args,
                                   (unsigned int)DYN_SHMEM, stream);
}

// Round 10
// 1395.224 us; speedup vs baseline: 1.4337x; 1.4337x over previous
//
#include <hip/hip_runtime.h>
#include <stdint.h>

#define Bsz 256
#define Tt  128
#define INs 256
#define Hh  512

typedef __attribute__((ext_vector_type(8))) short short8;
typedef __attribute__((ext_vector_type(4))) float f32x4;

__device__ __forceinline__ unsigned short f2bf(float f) {
  union { float f; unsigned int u; } v; v.f = f;
  unsigned int u = v.u;
  u += 0x7FFFu + ((u >> 16) & 1u);   // round-to-nearest-even
  return (unsigned short)(u >> 16);
}
__device__ __forceinline__ float bf2f(unsigned short h) {
  union { unsigned int u; float f; } v; v.u = ((unsigned int)h) << 16;
  return v.f;
}
__device__ __forceinline__ float sigf(float x) { return 1.0f / (1.0f + expf(-x)); }

#define AL(P)    __hip_atomic_load((P), __ATOMIC_RELAXED, __HIP_MEMORY_SCOPE_AGENT)
#define AS(P, V) __hip_atomic_store((P), (V), __ATOMIC_RELAXED, __HIP_MEMORY_SCOPE_AGENT)

union Q2S { unsigned long long q[2]; short8 s; };

// ---- ws layout (bytes) ----
// flags: [group][plane][cb] x 64B line, per layer: 4*4*32*64 = 32 KB
#define WS_F0 0
#define WS_F1 32768
#define WS_H0 65536                               // 4 slots x 256 x 512 bf16 = 1 MB
#define WS_H1 (WS_H0 + 4 * Bsz * Hh * 2)          // 2 slots x 256 KB
#define WS_ZERO_BYTES (WS_H1 + 2 * Bsz * Hh * 2)  // 1638400

#define W_BYTES   131072
#define DYN_SHMEM (W_BYTES + 64 * 4 + 48 * 4)

// poll this plane's 32 flags (64 lanes, each flag checked twice)
#define POLLW(BASE, TGT)                                                        \
  if ((TGT) > 0) {                                                              \
    const int* fp_ = (BASE) + ((lane & 31) << 4);                               \
    for (;;) {                                                                  \
      int v_ = AL(fp_);                                                         \
      if (__ballot(v_ >= (TGT)) == ~0ull) break;                                \
      __builtin_amdgcn_s_sleep(2);                                              \
    }                                                                           \
  }

// 16 ksteps of h-GEMM over one 16-row A plane, 8-deep coherent prefetch.
#define H_GEMM(PA, KB)                                                          \
  {                                                                             \
    unsigned long long pq[16];                                                  \
    _Pragma("unroll")                                                           \
    for (int s = 0; s < 8; ++s) {                                               \
      const unsigned long long* qa = (const unsigned long long*)((PA) + s * 32);\
      pq[s * 2] = AL(qa); pq[s * 2 + 1] = AL(qa + 1);                           \
    }                                                                           \
    _Pragma("unroll")                                                           \
    for (int ks = 0; ks < 16; ++ks) {                                           \
      const int sl = (ks & 7) << 1;                                             \
      Q2S u; u.q[0] = pq[sl]; u.q[1] = pq[sl + 1];                              \
      if (ks < 8) {                                                             \
        const unsigned long long* qa =                                          \
            (const unsigned long long*)((PA) + (ks + 8) * 32);                  \
        pq[sl] = AL(qa); pq[sl + 1] = AL(qa + 1);                               \
      }                                                                         \
      _Pragma("unroll")                                                         \
      for (int c4 = 0; c4 < 4; ++c4) {                                          \
        short8 b = *(const short8*)(smem + (((ks + (KB)) * 4 + c4) * 64 + lane) * 16); \
        acc[c4] = __builtin_amdgcn_mfma_f32_16x16x32_bf16(u.s, b, acc[c4], 0, 0, 0);   \
      }                                                                         \
    }                                                                           \
  }

// in-register peephole elementwise for one lane's 4 cells + u16 h stores
#define ELEMWISE(HDST)                                                          \
  {                                                                             \
    const int jj = lane & 15;                                                   \
    _Pragma("unroll")                                                           \
    for (int v = 0; v < 4; ++v) {                                               \
      const int R = (wave << 4) + ((lane >> 4) << 2) + v;                       \
      float gi = acc[0][v] + bxl[jj];                                           \
      float gf = acc[1][v] + bxl[16 + jj];                                      \
      float gg = acc[2][v] + bxl[32 + jj];                                      \
      float go = acc[3][v] + bxl[48 + jj];                                      \
      float co = cr[v];                                                         \
      float iv = sigf(gi + co * wcl[jj]);                                       \
      float fv = sigf(gf + co * wcl[16 + jj]);                                  \
      float gv = tanhf(gg);                                                     \
      float cn = fv * co + iv * gv;                                             \
      float ov = sigf(go + cn * wcl[32 + jj]);                                  \
      cr[v] = cn;                                                               \
      AS((HDST) + (size_t)((g << 6) + R) * Hh + j0 + jj,                        \
         f2bf(ov * tanhf(cn)));                                                 \
    }                                                                           \
  }

#define VM0() asm volatile("s_waitcnt vmcnt(0)" ::: "memory")

extern "C" __global__ void __launch_bounds__(256)
lstm_fused(const float* __restrict__ x,
           const float* __restrict__ Wx0, const float* __restrict__ bx0,
           const float* __restrict__ Wh0, const float* __restrict__ Wc0,
           const float* __restrict__ Wx1, const float* __restrict__ bx1,
           const float* __restrict__ Wh1, const float* __restrict__ Wc1,
           const float* __restrict__ Wfc, const float* __restrict__ bfc,
           float* __restrict__ out, unsigned char* __restrict__ ws)
{
  extern __shared__ char smem[];
  unsigned short* h0b = (unsigned short*)(ws + WS_H0);
  unsigned short* h1b = (unsigned short*)(ws + WS_H1);
  float* bxl = (float*)(smem + W_BYTES);
  float* wcl = bxl + 64;

  const int wg    = blockIdx.x;
  const int g     = wg >> 6;        // batch-row group (0..3), 64 rows each
  const int sub   = wg & 63;
  const int layer = sub >> 5;
  const int cb    = sub & 31;       // 16 hidden cols
  const int tid   = threadIdx.x;
  const int lane  = tid & 63;
  const int wave  = tid >> 6;       // wave-plane: rows g*64 + wave*16 .. +15
  const int j0    = cb << 4;

  // per-wave flag bases for this (group, plane)
  int* f0p = (int*)(ws + WS_F0) + (((g << 2) + wave) << 9);   // 32 flags x 16 ints
  int* f1p = (int*)(ws + WS_F1) + (((g << 2) + wave) << 9);
  int* myflag = (layer ? f1p : f0p) + (cb << 4);

  // ---- preload this WG's weight slice into LDS, bf16, fragment order ----
  {
    const int K   = layer ? 1024 : 768;
    const int k8s = K >> 3;
    const int ng  = 64 * k8s;
    for (int idx = tid; idx < ng; idx += 256) {
      const int nl = idx / k8s;
      const int k8 = idx - nl * k8s;
      const int k  = k8 << 3;
      const int nrow = (nl >> 4) * Hh + j0 + (nl & 15);
      const float* src;
      if (!layer) src = (k < INs) ? (Wx0 + (size_t)nrow * INs + k)
                                  : (Wh0 + (size_t)nrow * Hh + (k - INs));
      else        src = (k < Hh)  ? (Wx1 + (size_t)nrow * Hh + k)
                                  : (Wh1 + (size_t)nrow * Hh + (k - Hh));
      short8 v;
      #pragma unroll
      for (int j = 0; j < 8; ++j) v[j] = (short)f2bf(src[j]);
      const int slot = ((k8 >> 2) * 4 + (nl >> 4)) * 64 + ((k8 & 3) * 16 + (nl & 15));
      *(short8*)(smem + slot * 16) = v;
    }
  }
  {
    const float* bx = layer ? bx1 : bx0;
    const float* Wc = layer ? Wc1 : Wc0;
    if (tid < 64) bxl[tid] = bx[(tid >> 4) * Hh + j0 + (tid & 15)];
    if (tid < 48) wcl[tid] = Wc[(tid >> 4) * Hh + j0 + (tid & 15)];
  }
  __syncthreads();   // weights ready (only barrier before epilogue)

  // ---- wave tile: 16 rows x 64 gate-cols ----
  const int lr   = (wave << 4) + (lane & 15);   // local row 0..63
  const int koff = (lane >> 4) << 3;            // shorts
  const int bg   = (g << 6) + lr;               // global batch row

  float cr[4] = {0.f, 0.f, 0.f, 0.f};
  const f32x4 zz = {0.f, 0.f, 0.f, 0.f};

  if (!layer) {
    // =============== LAYER 0 ===============
    for (int t = 0; t < Tt; ++t) {
      f32x4 acc[4] = {zz, zz, zz, zz};
      // x-part first (peer-independent; overlaps peers' flag/data landing)
      const float* xp = x + ((size_t)bg * Tt + t) * INs + koff;
      #pragma unroll 2
      for (int ks = 0; ks < 8; ++ks) {
        const float* s0 = xp + ks * 32;
        short8 a;
        #pragma unroll
        for (int j = 0; j < 8; ++j) a[j] = (short)f2bf(s0[j]);
        #pragma unroll
        for (int c4 = 0; c4 < 4; ++c4) {
          short8 b = *(const short8*)(smem + ((ks * 4 + c4) * 64 + lane) * 16);
          acc[c4] = __builtin_amdgcn_mfma_f32_16x16x32_bf16(a, b, acc[c4], 0, 0, 0);
        }
      }
      POLLW(f0p, t)        // plane peers' h0[t-1] written
      const unsigned short* hp = h0b + (size_t)((t + 3) & 3) * (Bsz * Hh)
                                     + (size_t)bg * Hh + koff;
      H_GEMM(hp, 8)
      POLLW(f1p, t - 3)    // L1 plane consumed h0[t-4] -> slot t&3 reusable
      ELEMWISE(h0b + (size_t)(t & 3) * (Bsz * Hh))
      VM0();               // this wave's h stores visible at IF
      if (lane == 0) AS(myflag, t + 1);
    }
  } else {
    // =============== LAYER 1 ===============
    for (int u = 0; u < Tt; ++u) {
      f32x4 acc[4] = {zz, zz, zz, zz};
      POLLW(f1p, u)        // plane peers' h1[u-1] written
      const unsigned short* bp = h1b + (size_t)((u + 1) & 1) * (Bsz * Hh)
                                     + (size_t)bg * Hh + koff;
      H_GEMM(bp, 16)       // h1[u-1] @ Wh1 (ksteps 16..31)
      POLLW(f0p, u + 1)    // L0 plane's h0[u] written (L0 leads: usually ready)
      const unsigned short* ap = h0b + (size_t)(u & 3) * (Bsz * Hh)
                                     + (size_t)bg * Hh + koff;
      H_GEMM(ap, 0)        // h0[u] @ Wx1 (ksteps 0..15)
      ELEMWISE(h1b + (size_t)(u & 1) * (Bsz * Hh))
      VM0();
      if (lane == 0) AS(myflag, u + 1);
    }
  }

  // ---- epilogue: wait for my output group's 128 L1 wave-flags ----
  {
    const int og = wg >> 6;
    const int* fb = (int*)(ws + WS_F1) + (og << 11);   // 128 flags x 16 ints
    const int* fa = fb + (lane << 4);
    const int* fc = fb + ((lane + 64) << 4);
    for (;;) {
      int va = AL(fa), vb = AL(fc);
      if (__ballot((va >= Tt) && (vb >= Tt)) == ~0ull) break;
      __builtin_amdgcn_s_sleep(2);
    }
  }
  __builtin_amdgcn_fence(__ATOMIC_ACQUIRE, "agent");
  __builtin_amdgcn_sched_barrier(0);

  // ---- final FC: out[wg][0..7] = h1_final[wg] @ Wfc^T + bfc ----
  const unsigned short* hf = h1b + (size_t)(Bsz * Hh);  // slot 1 holds h1[127]
  float* red = (float*)smem;
  const int cc = tid & 7, ksl = tid >> 3;
  const unsigned short* hr = hf + (size_t)wg * Hh + ksl * 16;
  const float* wr = Wfc + (size_t)cc * Hh + ksl * 16;
  float s = 0.f;
  #pragma unroll
  for (int k = 0; k < 16; ++k) s += bf2f(hr[k]) * wr[k];
  __syncthreads();           // all waves done with weight-smem before reuse
  red[tid] = s;
  __syncthreads();
  if (tid < 8) {
    float a = bfc[tid];
    #pragma unroll
    for (int i = 0; i < 32; ++i) a += red[i * 8 + tid];
    out[wg * 8 + tid] = a;
  }
}

extern "C" void kernel_launch(void* const* d_in, const int* in_sizes, int n_in,
                              void* d_out, int out_size, void* d_ws, size_t ws_size,
                              hipStream_t stream) {
  if (ws_size < (size_t)WS_ZERO_BYTES) return;

  const float* x   = (const float*)d_in[0];
  const float* Wx0 = (const float*)d_in[1];
  const float* bx0 = (const float*)d_in[2];
  const float* Wh0 = (const float*)d_in[3];
  const float* Wc0 = (const float*)d_in[4];
  const float* Wx1 = (const float*)d_in[5];
  const float* bx1 = (const float*)d_in[6];
  const float* Wh1 = (const float*)d_in[7];
  const float* Wc1 = (const float*)d_in[8];
  const float* Wfc = (const float*)d_in[9];
  const float* bfc = (const float*)d_in[10];
  float* out = (float*)d_out;
  unsigned char* ws = (unsigned char*)d_ws;

  (void)hipMemsetAsync(d_ws, 0, WS_ZERO_BYTES, stream);
  (void)hipFuncSetAttribute(reinterpret_cast<const void*>(lstm_fused),
                            hipFuncAttributeMaxDynamicSharedMemorySize, DYN_SHMEM);
  void* args[] = {&x, &Wx0, &bx0, &Wh0, &Wc0, &Wx1, &bx1, &Wh1, &Wc1, &Wfc, &bfc, &out, &ws};
  (void)hipLaunchCooperativeKernel((void*)lstm_fused, dim3(256), dim3(256), args,
                                   (unsigned int)DYN_SHMEM, stream);
}

// Round 11
// 1179.386 us; speedup vs baseline: 1.6960x; 1.1830x over previous
//
#include <hip/hip_runtime.h>
#include <stdint.h>

#define Bsz 256
#define Tt  128
#define INs 256
#define Hh  512

typedef __attribute__((ext_vector_type(8))) short short8;
typedef __attribute__((ext_vector_type(4))) float f32x4;

__device__ __forceinline__ unsigned short f2bf(float f) {
  union { float f; unsigned int u; } v; v.f = f;
  unsigned int u = v.u;
  u += 0x7FFFu + ((u >> 16) & 1u);   // round-to-nearest-even
  return (unsigned short)(u >> 16);
}
__device__ __forceinline__ float bf2f(unsigned short h) {
  union { unsigned int u; float f; } v; v.u = ((unsigned int)h) << 16;
  return v.f;
}
__device__ __forceinline__ float sigf(float x) { return 1.0f / (1.0f + expf(-x)); }

#define AL(P)    __hip_atomic_load((P), __ATOMIC_RELAXED, __HIP_MEMORY_SCOPE_AGENT)
#define AS(P, V) __hip_atomic_store((P), (V), __ATOMIC_RELAXED, __HIP_MEMORY_SCOPE_AGENT)

union Q2S { unsigned long long q[2]; short8 s; };

// ---- ws layout (bytes) ----
// flags: [group][plane][cb] x 64B line, per layer: 4*4*32*64 = 32 KB
#define WS_F0 0
#define WS_F1 32768
#define WS_H0 65536                               // 4 slots x 256 x 512 bf16 = 1 MB
#define WS_H1 (WS_H0 + 4 * Bsz * Hh * 2)          // 2 slots x 256 KB
#define WS_ZERO_BYTES (WS_H1 + 2 * Bsz * Hh * 2)  // 1638400

#define W_BYTES   131072
#define DYN_SHMEM (W_BYTES + 64 * 4 + 48 * 4)

// poll this plane's 32 flags (64 lanes, each flag checked twice)
#define POLLW(BASE, TGT)                                                        \
  if ((TGT) > 0) {                                                              \
    const int* fp_ = (BASE) + ((lane & 31) << 4);                               \
    for (;;) {                                                                  \
      int v_ = AL(fp_);                                                         \
      if (__ballot(v_ >= (TGT)) == ~0ull) break;                                \
      __builtin_amdgcn_s_sleep(2);                                              \
    }                                                                           \
  }

// 16 ksteps of h-GEMM over one 16-row A plane; ALL 32 u64 loads issued
// back-to-back first (single latency exposure), then the MFMA block.
#define H_GEMM(PA, KB)                                                          \
  {                                                                             \
    unsigned long long pq[32];                                                  \
    _Pragma("unroll")                                                           \
    for (int s = 0; s < 16; ++s) {                                              \
      const unsigned long long* qa = (const unsigned long long*)((PA) + s * 32);\
      pq[s * 2] = AL(qa); pq[s * 2 + 1] = AL(qa + 1);                           \
    }                                                                           \
    _Pragma("unroll")                                                           \
    for (int ks = 0; ks < 16; ++ks) {                                           \
      Q2S u; u.q[0] = pq[ks * 2]; u.q[1] = pq[ks * 2 + 1];                      \
      _Pragma("unroll")                                                         \
      for (int c4 = 0; c4 < 4; ++c4) {                                          \
        short8 b = *(const short8*)(smem + (((ks + (KB)) * 4 + c4) * 64 + lane) * 16); \
        acc[c4] = __builtin_amdgcn_mfma_f32_16x16x32_bf16(u.s, b, acc[c4], 0, 0, 0);   \
      }                                                                         \
    }                                                                           \
  }

// in-register peephole elementwise for one lane's 4 cells + u16 h stores
#define ELEMWISE(HDST)                                                          \
  {                                                                             \
    const int jj = lane & 15;                                                   \
    _Pragma("unroll")                                                           \
    for (int v = 0; v < 4; ++v) {                                               \
      const int R = (wave << 4) + ((lane >> 4) << 2) + v;                       \
      float gi = acc[0][v] + bxl[jj];                                           \
      float gf = acc[1][v] + bxl[16 + jj];                                      \
      float gg = acc[2][v] + bxl[32 + jj];                                      \
      float go = acc[3][v] + bxl[48 + jj];                                      \
      float co = cr[v];                                                         \
      float iv = sigf(gi + co * wcl[jj]);                                       \
      float fv = sigf(gf + co * wcl[16 + jj]);                                  \
      float gv = tanhf(gg);                                                     \
      float cn = fv * co + iv * gv;                                             \
      float ov = sigf(go + cn * wcl[32 + jj]);                                  \
      cr[v] = cn;                                                               \
      AS((HDST) + (size_t)((g << 6) + R) * Hh + j0 + jj,                        \
         f2bf(ov * tanhf(cn)));                                                 \
    }                                                                           \
  }

#define VM0() asm volatile("s_waitcnt vmcnt(0)" ::: "memory")

extern "C" __global__ void __launch_bounds__(256)
lstm_fused(const float* __restrict__ x,
           const float* __restrict__ Wx0, const float* __restrict__ bx0,
           const float* __restrict__ Wh0, const float* __restrict__ Wc0,
           const float* __restrict__ Wx1, const float* __restrict__ bx1,
           const float* __restrict__ Wh1, const float* __restrict__ Wc1,
           const float* __restrict__ Wfc, const float* __restrict__ bfc,
           float* __restrict__ out, unsigned char* __restrict__ ws)
{
  extern __shared__ char smem[];
  unsigned short* h0b = (unsigned short*)(ws + WS_H0);
  unsigned short* h1b = (unsigned short*)(ws + WS_H1);
  float* bxl = (float*)(smem + W_BYTES);
  float* wcl = bxl + 64;

  const int wg    = blockIdx.x;
  const int g     = wg >> 6;        // batch-row group (0..3), 64 rows each
  const int sub   = wg & 63;
  const int layer = sub >> 5;
  const int cb    = sub & 31;       // 16 hidden cols
  const int tid   = threadIdx.x;
  const int lane  = tid & 63;
  const int wave  = tid >> 6;       // wave-plane: rows g*64 + wave*16 .. +15
  const int j0    = cb << 4;

  // per-wave flag bases for this (group, plane)
  int* f0p = (int*)(ws + WS_F0) + (((g << 2) + wave) << 9);   // 32 flags x 16 ints
  int* f1p = (int*)(ws + WS_F1) + (((g << 2) + wave) << 9);
  int* myflag = (layer ? f1p : f0p) + (cb << 4);

  // ---- preload this WG's weight slice into LDS, bf16, fragment order ----
  {
    const int K   = layer ? 1024 : 768;
    const int k8s = K >> 3;
    const int ng  = 64 * k8s;
    for (int idx = tid; idx < ng; idx += 256) {
      const int nl = idx / k8s;
      const int k8 = idx - nl * k8s;
      const int k  = k8 << 3;
      const int nrow = (nl >> 4) * Hh + j0 + (nl & 15);
      const float* src;
      if (!layer) src = (k < INs) ? (Wx0 + (size_t)nrow * INs + k)
                                  : (Wh0 + (size_t)nrow * Hh + (k - INs));
      else        src = (k < Hh)  ? (Wx1 + (size_t)nrow * Hh + k)
                                  : (Wh1 + (size_t)nrow * Hh + (k - Hh));
      short8 v;
      #pragma unroll
      for (int j = 0; j < 8; ++j) v[j] = (short)f2bf(src[j]);
      const int slot = ((k8 >> 2) * 4 + (nl >> 4)) * 64 + ((k8 & 3) * 16 + (nl & 15));
      *(short8*)(smem + slot * 16) = v;
    }
  }
  {
    const float* bx = layer ? bx1 : bx0;
    const float* Wc = layer ? Wc1 : Wc0;
    if (tid < 64) bxl[tid] = bx[(tid >> 4) * Hh + j0 + (tid & 15)];
    if (tid < 48) wcl[tid] = Wc[(tid >> 4) * Hh + j0 + (tid & 15)];
  }
  __syncthreads();   // weights ready (only barrier before epilogue)

  // ---- wave tile: 16 rows x 64 gate-cols ----
  const int lr   = (wave << 4) + (lane & 15);   // local row 0..63
  const int koff = (lane >> 4) << 3;            // shorts
  const int bg   = (g << 6) + lr;               // global batch row

  float cr[4] = {0.f, 0.f, 0.f, 0.f};
  const f32x4 zz = {0.f, 0.f, 0.f, 0.f};

  if (!layer) {
    // =============== LAYER 0 ===============
    for (int t = 0; t < Tt; ++t) {
      f32x4 acc[4] = {zz, zz, zz, zz};
      // x-part first: peer-independent, fills the flag-wait window
      const float* xp = x + ((size_t)bg * Tt + t) * INs + koff;
      #pragma unroll 2
      for (int ks = 0; ks < 8; ++ks) {
        const float* s0 = xp + ks * 32;
        short8 a;
        #pragma unroll
        for (int j = 0; j < 8; ++j) a[j] = (short)f2bf(s0[j]);
        #pragma unroll
        for (int c4 = 0; c4 < 4; ++c4) {
          short8 b = *(const short8*)(smem + ((ks * 4 + c4) * 64 + lane) * 16);
          acc[c4] = __builtin_amdgcn_mfma_f32_16x16x32_bf16(a, b, acc[c4], 0, 0, 0);
        }
      }
      POLLW(f0p, t)        // plane peers' h0[t-1] written
      POLLW(f1p, t - 3)    // L1 plane consumed h0[t-4] -> slot t&3 reusable
      const unsigned short* hp = h0b + (size_t)((t + 3) & 3) * (Bsz * Hh)
                                     + (size_t)bg * Hh + koff;
      H_GEMM(hp, 8)
      ELEMWISE(h0b + (size_t)(t & 3) * (Bsz * Hh))
      VM0();               // this wave's h stores visible at IF
      if (lane == 0) AS(myflag, t + 1);
    }
  } else {
    // =============== LAYER 1 ===============
    for (int u = 0; u < Tt; ++u) {
      f32x4 acc[4] = {zz, zz, zz, zz};
      // h0 half FIRST: L0 leads via the ring, f0 is ~always satisfied ->
      // this GEMM executes inside the f1 wait window.
      POLLW(f0p, u + 1)    // L0 plane's h0[u] written
      const unsigned short* ap = h0b + (size_t)(u & 3) * (Bsz * Hh)
                                     + (size_t)bg * Hh + koff;
      H_GEMM(ap, 0)        // h0[u] @ Wx1 (ksteps 0..15)
      // tight own-layer dependency LAST: exposed tail is only this half
      POLLW(f1p, u)        // plane peers' h1[u-1] written
      const unsigned short* bp = h1b + (size_t)((u + 1) & 1) * (Bsz * Hh)
                                     + (size_t)bg * Hh + koff;
      H_GEMM(bp, 16)       // h1[u-1] @ Wh1 (ksteps 16..31)
      ELEMWISE(h1b + (size_t)(u & 1) * (Bsz * Hh))
      VM0();
      if (lane == 0) AS(myflag, u + 1);
    }
  }

  // ---- epilogue: wait for my output group's 128 L1 wave-flags ----
  {
    const int og = wg >> 6;
    const int* fb = (int*)(ws + WS_F1) + (og << 11);   // 128 flags x 16 ints
    const int* fa = fb + (lane << 4);
    const int* fc = fb + ((lane + 64) << 4);
    for (;;) {
      int va = AL(fa), vb = AL(fc);
      if (__ballot((va >= Tt) && (vb >= Tt)) == ~0ull) break;
      __builtin_amdgcn_s_sleep(2);
    }
  }
  __builtin_amdgcn_fence(__ATOMIC_ACQUIRE, "agent");
  __builtin_amdgcn_sched_barrier(0);

  // ---- final FC: out[wg][0..7] = h1_final[wg] @ Wfc^T + bfc ----
  const unsigned short* hf = h1b + (size_t)(Bsz * Hh);  // slot 1 holds h1[127]
  float* red = (float*)smem;
  const int cc = tid & 7, ksl = tid >> 3;
  const unsigned short* hr = hf + (size_t)wg * Hh + ksl * 16;
  const float* wr = Wfc + (size_t)cc * Hh + ksl * 16;
  float s = 0.f;
  #pragma unroll
  for (int k = 0; k < 16; ++k) s += bf2f(hr[k]) * wr[k];
  __syncthreads();           // all waves done with weight-smem before reuse
  red[tid] = s;
  __syncthreads();
  if (tid < 8) {
    float a = bfc[tid];
    #pragma unroll
    for (int i = 0; i < 32; ++i) a += red[i * 8 + tid];
    out[wg * 8 + tid] = a;
  }
}

extern "C" void kernel_launch(void* const* d_in, const int* in_sizes, int n_in,
                              void* d_out, int out_size, void* d_ws, size_t ws_size,
                              hipStream_t stream) {
  if (ws_size < (size_t)WS_ZERO_BYTES) return;

  const float* x   = (const float*)d_in[0];
  const float* Wx0 = (const float*)d_in[1];
  const float* bx0 = (const float*)d_in[2];
  const float* Wh0 = (const float*)d_in[3];
  const float* Wc0 = (const float*)d_in[4];
  const float* Wx1 = (const float*)d_in[5];
  const float* bx1 = (const float*)d_in[6];
  const float* Wh1 = (const float*)d_in[7];
  const float* Wc1 = (const float*)d_in[8];
  const float* Wfc = (const float*)d_in[9];
  const float* bfc = (const float*)d_in[10];
  float* out = (float*)d_out;
  unsigned char* ws = (unsigned char*)d_ws;

  (void)hipMemsetAsync(d_ws, 0, WS_ZERO_BYTES, stream);
  (void)hipFuncSetAttribute(reinterpret_cast<const void*>(lstm_fused),
                            hipFuncAttributeMaxDynamicSharedMemorySize, DYN_SHMEM);
  void* args[] = {&x, &Wx0, &bx0, &Wh0, &Wc0, &Wx1, &bx1, &Wh1, &Wc1, &Wfc, &bfc, &out, &ws};
  (void)hipLaunchCooperativeKernel((void*)lstm_fused, dim3(256), dim3(256), args,
                                   (unsigned int)DYN_SHMEM, stream);
}